// Round 11
// baseline (371.752 us; speedup 1.0000x reference)
//
#include <hip/hip_runtime.h>
#include <math.h>

#define NPIX 4096
#define CR   64
#define CIN  256
#define HW   64
#define CSPLIT 8    // conv c-split partials

typedef __attribute__((ext_vector_type(8))) short s16x8;
typedef __attribute__((ext_vector_type(4))) float f32x4;

__device__ __forceinline__ unsigned short f2bf(float f) {
  union { float f; unsigned u; } a; a.f = f;
  return (unsigned short)((a.u + 0x7FFF + ((a.u >> 16) & 1)) >> 16);
}
__device__ __forceinline__ float bf2f(unsigned short h) {
  union { unsigned u; float f; } a; a.u = (unsigned)h << 16; return a.f;
}

// ---------------------------------------------------------------------------
// K1: conv partials, c-split=8. Block: 2h x 64w x 32d over 32 channels.
// ---------------------------------------------------------------------------
__global__ __launch_bounds__(256) void k_conv_part(
    const float* __restrict__ x, const float* __restrict__ cw,
    float* __restrict__ pp) {
  const int hg = blockIdx.x;
  const int dg = blockIdx.y;
  const int b  = blockIdx.z >> 3;
  const int cs = blockIdx.z & 7;
  const int h0 = hg * 2, d0 = dg * 32, c0 = cs * 32;
  const int tid = threadIdx.x;
  const int wp = tid & 31;
  const int dq = tid >> 5;
  const int w0 = wp * 2;

  __shared__ float xs[16][4][68];
  __shared__ float wl[16][9][32];

  float acc[2][2][4] = {};

  for (int cc = 0; cc < 32; cc += 16) {
    __syncthreads();
    for (int i = tid; i < 16 * 256; i += 256) {
      int c = i >> 8, r = (i >> 6) & 3, w = i & 63;
      int row = h0 - 1 + r;
      float v = 0.f;
      if (row >= 0 && row < HW)
        v = x[((size_t)(b * CIN + c0 + cc + c) << 12) + row * HW + w];
      xs[c][r][w + 1] = v;
    }
    if (tid < 128) {
      int c = tid >> 3, r = (tid >> 1) & 3, s = tid & 1;
      xs[c][r][s ? 65 : 0] = 0.f;
    }
    for (int i = tid; i < 16 * 9 * 32; i += 256) {
      int c = i / 288, rem = i - c * 288, tap = rem >> 5, d = rem & 31;
      wl[c][tap][d] = cw[(size_t)(d0 + d) * 2304 + (c0 + cc + c) * 9 + tap];
    }
    __syncthreads();

#pragma unroll 2
    for (int c = 0; c < 16; ++c) {
      float xv[4][4];
#pragma unroll
      for (int r = 0; r < 4; ++r) {
        float2 p0 = *(const float2*)&xs[c][r][w0];
        float2 p1 = *(const float2*)&xs[c][r][w0 + 2];
        xv[r][0] = p0.x; xv[r][1] = p0.y; xv[r][2] = p1.x; xv[r][3] = p1.y;
      }
#pragma unroll
      for (int tap = 0; tap < 9; ++tap) {
        const int kh = tap / 3, kw = tap - kh * 3;
        float4 wv = *(const float4*)&wl[c][tap][dq * 4];
        float wf[4] = {wv.x, wv.y, wv.z, wv.w};
#pragma unroll
        for (int hi = 0; hi < 2; ++hi)
#pragma unroll
          for (int wi = 0; wi < 2; ++wi) {
            float xvv = xv[hi + kh][wi + kw];
#pragma unroll
            for (int di = 0; di < 4; ++di)
              acc[hi][wi][di] = fmaf(wf[di], xvv, acc[hi][wi][di]);
          }
      }
    }
  }
#pragma unroll
  for (int di = 0; di < 4; ++di) {
    int d = d0 + dq * 4 + di;
#pragma unroll
    for (int hi = 0; hi < 2; ++hi)
#pragma unroll
      for (int wi = 0; wi < 2; ++wi)
        pp[((size_t)((b * CSPLIT + cs) * 64 + d) << 12) + (h0 + hi) * HW + w0 + wi] =
            acc[hi][wi][di];
  }
}

// ---------------------------------------------------------------------------
// K2: reduce partials + bias + BN + PReLU, split e into bf16 hi/lo, write
// eT [b][n_phys][64]; n -> phys: g=n>>8, i=n&255, np=(g<<8)|((i&15)<<4)|(i>>4)
// ---------------------------------------------------------------------------
__global__ __launch_bounds__(256) void k_bn(
    const float* __restrict__ pp, const float* __restrict__ cb,
    const float* __restrict__ gamma, const float* __restrict__ beta,
    const float* __restrict__ mean, const float* __restrict__ var,
    const float* __restrict__ pw, unsigned short* __restrict__ eTh,
    unsigned short* __restrict__ eTl) {
  const int n0 = blockIdx.x * 64;
  const int b  = blockIdx.y;
  const int tid = threadIdx.x;
  __shared__ float et[64][65];

  const float slope = pw[0];
#pragma unroll 4
  for (int dd = 0; dd < 16; ++dd) {
    int d = dd * 4 + (tid >> 6);
    int n = tid & 63;
    float s = 0.f;
#pragma unroll
    for (int cs = 0; cs < CSPLIT; ++cs)
      s += pp[((size_t)((b * CSPLIT + cs) * 64 + d) << 12) + n0 + n];
    float scale = gamma[d] / sqrtf(var[d] + 1e-5f);
    float y = (s + cb[d] - mean[d]) * scale + beta[d];
    y = (y >= 0.f) ? y : slope * y;
    et[d][n] = y;
  }
  __syncthreads();
#pragma unroll 4
  for (int w = 0; w < 16; ++w) {
    int n = w * 4 + (tid >> 6);
    int d = tid & 63;
    float v = et[d][n];
    unsigned short hi = f2bf(v);
    unsigned short lo = f2bf(v - bf2f(hi));
    int nl = n0 + n;
    int g = nl >> 8, i = nl & 255;
    int np = (g << 8) | ((i & 15) << 4) | (i >> 4);
    size_t off = (((size_t)b << 12) + np) * 64 + d;
    eTh[off] = hi;
    eTl[off] = lo;
  }
}

// ---------------------------------------------------------------------------
// K3: Gram via split-bf16 MFMA + in-register Michelot sparsemax.
// 1024 thr (16 waves); block = 32-row stripe x 4096 cols; wave = 256 cols,
// 2 row-groups. A-fragments hoisted to regs; per tile t: 4 independent 16B
// B-loads (full 128B eT row) + 12 MFMAs. Coalesced sparse b128 stores.
// ---------------------------------------------------------------------------
__global__ __launch_bounds__(1024) void k_gsm(
    const unsigned short* __restrict__ eTh, const unsigned short* __restrict__ eTl,
    unsigned short* __restrict__ p, unsigned char* __restrict__ flags) {
  const int n0 = blockIdx.x * 32;
  const int b  = blockIdx.y;
  const int tid = threadIdx.x;
  const int l = tid & 63, wid = tid >> 6;   // 16 waves
  const int lc = l & 15, lq = l >> 4;

  __shared__ __align__(16) unsigned short eah[32][72];
  __shared__ __align__(16) unsigned short eal[32][72];
  __shared__ float rs[16][32];
  __shared__ int   rc[16][32];
  __shared__ float stau[32];
  __shared__ int   sprev[32];
  __shared__ int   schg;

  const size_t ebase = ((size_t)b << 12) * 64;   // b*4096*64

  // stage A stripe: logical rows n0..n0+31 (phys-permuted source)
  for (int idx = tid; idx < 32 * 64; idx += 1024) {
    int d = idx & 63, r = idx >> 6;
    int nl = n0 + r;
    int g = nl >> 8, i = nl & 255;
    int np = (g << 8) | ((i & 15) << 4) | (i >> 4);
    size_t off = ebase + (size_t)np * 64 + d;
    eah[r][d] = eTh[off];
    eal[r][d] = eTl[off];
  }
  if (tid < 32) sprev[tid] = NPIX + 1;
  __syncthreads();

  // hoist A fragments: [group][kc], hi/lo
  s16x8 Ah[2][2], Al[2][2];
#pragma unroll
  for (int g = 0; g < 2; ++g)
#pragma unroll
    for (int kc = 0; kc < 2; ++kc) {
      Ah[g][kc] = *(const s16x8*)&eah[g * 16 + lc][kc * 32 + lq * 8];
      Al[g][kc] = *(const s16x8*)&eal[g * 16 + lc][kc * 32 + lq * 8];
    }

  f32x4 acc[2][16];
#pragma unroll
  for (int g = 0; g < 2; ++g)
#pragma unroll
    for (int t = 0; t < 16; ++t)
#pragma unroll
      for (int q = 0; q < 4; ++q) acc[g][t][q] = 0.f;

  const int mbase = wid * 256;
#pragma unroll 4
  for (int t = 0; t < 16; ++t) {
    size_t off = ebase + (size_t)(mbase + t * 16 + lc) * 64 + lq * 8;
    s16x8 bh0 = *(const s16x8*)&eTh[off];
    s16x8 bh1 = *(const s16x8*)&eTh[off + 32];
    s16x8 bl0 = *(const s16x8*)&eTl[off];
    s16x8 bl1 = *(const s16x8*)&eTl[off + 32];
#pragma unroll
    for (int g = 0; g < 2; ++g) {
      acc[g][t] = __builtin_amdgcn_mfma_f32_16x16x32_bf16(Ah[g][0], bh0, acc[g][t], 0, 0, 0);
      acc[g][t] = __builtin_amdgcn_mfma_f32_16x16x32_bf16(Ah[g][0], bl0, acc[g][t], 0, 0, 0);
      acc[g][t] = __builtin_amdgcn_mfma_f32_16x16x32_bf16(Al[g][0], bh0, acc[g][t], 0, 0, 0);
      acc[g][t] = __builtin_amdgcn_mfma_f32_16x16x32_bf16(Ah[g][1], bh1, acc[g][t], 0, 0, 0);
      acc[g][t] = __builtin_amdgcn_mfma_f32_16x16x32_bf16(Ah[g][1], bl1, acc[g][t], 0, 0, 0);
      acc[g][t] = __builtin_amdgcn_mfma_f32_16x16x32_bf16(Al[g][1], bh1, acc[g][t], 0, 0, 0);
    }
  }

  // tau init = rowmax - 1   (row r = g*16 + lq*4 + q)
  {
    float mx[2][4];
#pragma unroll
    for (int g = 0; g < 2; ++g)
#pragma unroll
      for (int q = 0; q < 4; ++q) {
        float m = acc[g][0][q];
#pragma unroll
        for (int t = 1; t < 16; ++t) m = fmaxf(m, acc[g][t][q]);
        mx[g][q] = m;
      }
#pragma unroll
    for (int o = 1; o <= 8; o <<= 1)
#pragma unroll
      for (int g = 0; g < 2; ++g)
#pragma unroll
        for (int q = 0; q < 4; ++q) mx[g][q] = fmaxf(mx[g][q], __shfl_xor(mx[g][q], o));
    if (lc == 0)
#pragma unroll
      for (int g = 0; g < 2; ++g)
#pragma unroll
        for (int q = 0; q < 4; ++q) rs[wid][g * 16 + lq * 4 + q] = mx[g][q];
  }
  __syncthreads();
  if (tid < 32) {
    float m = rs[0][tid];
#pragma unroll
    for (int w = 1; w < 16; ++w) m = fmaxf(m, rs[w][tid]);
    stau[tid] = m - 1.0f;
  }

  // Michelot iterations
  for (int it = 0; it < 64; ++it) {
    __syncthreads();
    float tl[2][4];
#pragma unroll
    for (int g = 0; g < 2; ++g)
#pragma unroll
      for (int q = 0; q < 4; ++q) tl[g][q] = stau[g * 16 + lq * 4 + q];
    if (tid == 0) schg = 0;
    float s[2][4]; int c[2][4];
#pragma unroll
    for (int g = 0; g < 2; ++g)
#pragma unroll
      for (int q = 0; q < 4; ++q) { s[g][q] = 0.f; c[g][q] = 0; }
#pragma unroll
    for (int t = 0; t < 16; ++t)
#pragma unroll
      for (int g = 0; g < 2; ++g)
#pragma unroll
        for (int q = 0; q < 4; ++q) {
          float v = acc[g][t][q];
          if (v > tl[g][q]) { s[g][q] += v; ++c[g][q]; }
        }
#pragma unroll
    for (int o = 1; o <= 8; o <<= 1)
#pragma unroll
      for (int g = 0; g < 2; ++g)
#pragma unroll
        for (int q = 0; q < 4; ++q) {
          s[g][q] += __shfl_xor(s[g][q], o);
          c[g][q] += __shfl_xor(c[g][q], o);
        }
    if (lc == 0)
#pragma unroll
      for (int g = 0; g < 2; ++g)
#pragma unroll
        for (int q = 0; q < 4; ++q) {
          rs[wid][g * 16 + lq * 4 + q] = s[g][q];
          rc[wid][g * 16 + lq * 4 + q] = c[g][q];
        }
    __syncthreads();
    if (tid < 32) {
      float ss = 0.f; int cc = 0;
#pragma unroll
      for (int w = 0; w < 16; ++w) { ss += rs[w][tid]; cc += rc[w][tid]; }
      stau[tid] = (ss - 1.f) / (float)cc;
      if (cc != sprev[tid]) { sprev[tid] = cc; schg = 1; }
    }
    __syncthreads();
    if (schg == 0) break;
  }

  // p: lane patch per group = 4 rows x 16 contiguous cols; sparse b128 stores
  float tw[2][4];
#pragma unroll
  for (int g = 0; g < 2; ++g)
#pragma unroll
    for (int q = 0; q < 4; ++q) tw[g][q] = stau[g * 16 + lq * 4 + q];
  const unsigned long long M0 = 0x00FF00FF00FF00FFULL;  // lanes lc<8
#pragma unroll
  for (int g = 0; g < 2; ++g) {
    s16x8 oA[4], oB[4];
    int anyL = 0;
#pragma unroll
    for (int q = 0; q < 4; ++q) {
#pragma unroll
      for (int t = 0; t < 8; ++t) {
        float pv = fmaxf(acc[g][t][q] - tw[g][q], 0.f);
        anyL |= (pv > 0.f);
        oA[q][t] = (short)f2bf(pv);
      }
#pragma unroll
      for (int t = 0; t < 8; ++t) {
        float pv = fmaxf(acc[g][t + 8][q] - tw[g][q], 0.f);
        anyL |= (pv > 0.f);
        oB[q][t] = (short)f2bf(pv);
      }
    }
    unsigned long long bal = __ballot(anyL != 0);
    bool w0 = (bal & M0) != 0;
    bool w1 = (bal & ~M0) != 0;
    bool mine = (lc < 8) ? w0 : w1;
    if (mine) {
#pragma unroll
      for (int q = 0; q < 4; ++q) {
        unsigned short* pr =
            p + ((size_t)(b * NPIX + n0 + g * 16 + lq * 4 + q) << 12) + mbase + lc * 16;
        *(s16x8*)pr = oA[q];
        *(s16x8*)(pr + 8) = oB[q];
      }
    }
    if (l == 0) {
      int stripe = blockIdx.x * 2 + g;             // 16-row stripe id, 0..255
      if (w0) flags[(b << 13) | ((wid * 2 + 0) << 8) | stripe] = 1;
      if (w1) flags[(b << 13) | ((wid * 2 + 1) << 8) | stripe] = 1;
    }
  }
}

// ---------------------------------------------------------------------------
// K4: out = x @ p + x, bf16 MFMA, skipping zero k-tiles; zero-fill halves
// whose 16-row flag is unset (their p was never written).
// ---------------------------------------------------------------------------
__global__ __launch_bounds__(256) void k_out_mfma(
    const unsigned short* __restrict__ pb, const float* __restrict__ x,
    float* __restrict__ out, const unsigned char* __restrict__ flags) {
  const int m0 = blockIdx.x * 128;
  const int c0 = blockIdx.y * 64;
  const int b  = blockIdx.z;
  const int tid = threadIdx.x;
  const int l = tid & 63, wid = tid >> 6;
  const int wr = wid >> 1, wc = wid & 1;

  __shared__ unsigned short As[64][42];
  __shared__ unsigned short Bs[128][42];
  __shared__ unsigned char fl[256];

  fl[tid] = flags[(b << 13) | (blockIdx.x << 8) | tid];   // 256 stripes

  f32x4 acc[2][4];
#pragma unroll
  for (int i = 0; i < 2; ++i)
#pragma unroll
    for (int j = 0; j < 4; ++j)
#pragma unroll
      for (int q = 0; q < 4; ++q) acc[i][j][q] = 0.f;

  const int arow = tid >> 2;
  const int akc  = (tid & 3) * 8;
  const float* axsrc = x + ((size_t)(b * CIN + c0 + arow) << 12) + akc;
  const int bm = (tid & 31) * 4;
  const int bk = (tid >> 5) * 4;
  const unsigned short* bsrc = pb + ((size_t)(b * NPIX + bk) << 12) + m0 + bm;
  const int myhalf = bk >> 4;                 // 0: rows 0..15, 1: 16..31

  __syncthreads();                    // fl ready

  for (int k0 = 0; k0 < NPIX; k0 += 32) {
    const int s0 = k0 >> 4;
    const int have0 = fl[s0], have1 = fl[s0 + 1];
    if (!have0 && !have1) continue;   // block-uniform skip
    __syncthreads();
    float4 A0 = *(const float4*)(axsrc + k0);
    float4 A1 = *(const float4*)(axsrc + k0 + 4);
    s16x8 ap;
    ap[0] = (short)f2bf(A0.x); ap[1] = (short)f2bf(A0.y);
    ap[2] = (short)f2bf(A0.z); ap[3] = (short)f2bf(A0.w);
    ap[4] = (short)f2bf(A1.x); ap[5] = (short)f2bf(A1.y);
    ap[6] = (short)f2bf(A1.z); ap[7] = (short)f2bf(A1.w);
    *(s16x8*)&As[arow][akc] = ap;
    if ((myhalf ? have1 : have0)) {
      const unsigned short* bp = bsrc + ((size_t)k0 << 12);
      ushort4 L0 = *(const ushort4*)(bp);
      ushort4 L1 = *(const ushort4*)(bp + 4096);
      ushort4 L2 = *(const ushort4*)(bp + 8192);
      ushort4 L3 = *(const ushort4*)(bp + 12288);
      *(ushort4*)&Bs[bm + 0][bk] = make_ushort4(L0.x, L1.x, L2.x, L3.x);
      *(ushort4*)&Bs[bm + 1][bk] = make_ushort4(L0.y, L1.y, L2.y, L3.y);
      *(ushort4*)&Bs[bm + 2][bk] = make_ushort4(L0.z, L1.z, L2.z, L3.z);
      *(ushort4*)&Bs[bm + 3][bk] = make_ushort4(L0.w, L1.w, L2.w, L3.w);
    } else {
      ushort4 zz = make_ushort4(0, 0, 0, 0);
      *(ushort4*)&Bs[bm + 0][bk] = zz;
      *(ushort4*)&Bs[bm + 1][bk] = zz;
      *(ushort4*)&Bs[bm + 2][bk] = zz;
      *(ushort4*)&Bs[bm + 3][bk] = zz;
    }
    __syncthreads();

    s16x8 a[2], bb[4];
    const int kg = l >> 4;
#pragma unroll
    for (int i = 0; i < 2; ++i) {
      int row = wr * 32 + i * 16 + (l & 15);
      a[i] = *(const s16x8*)&As[row][kg * 8];
    }
#pragma unroll
    for (int j = 0; j < 4; ++j) {
      int n = wc * 64 + j * 16 + (l & 15);
      bb[j] = *(const s16x8*)&Bs[n][kg * 8];
    }
#pragma unroll
    for (int i = 0; i < 2; ++i)
#pragma unroll
      for (int j = 0; j < 4; ++j)
        acc[i][j] = __builtin_amdgcn_mfma_f32_16x16x32_bf16(
            a[i], bb[j], acc[i][j], 0, 0, 0);
  }

#pragma unroll
  for (int i = 0; i < 2; ++i)
#pragma unroll
    for (int j = 0; j < 4; ++j)
#pragma unroll
      for (int q = 0; q < 4; ++q) {
        int c = c0 + wr * 32 + i * 16 + (l >> 4) * 4 + q;
        int m = m0 + wc * 64 + j * 16 + (l & 15);
        size_t off = ((size_t)(b * CIN + c) << 12) + m;
        out[off] = acc[i][j][q] + x[off];
      }
}

// ---------------------------------------------------------------------------
extern "C" void kernel_launch(void* const* d_in, const int* in_sizes, int n_in,
                              void* d_out, int out_size, void* d_ws, size_t ws_size,
                              hipStream_t stream) {
  const float* x     = (const float*)d_in[0];
  const float* cw    = (const float*)d_in[1];
  const float* cb    = (const float*)d_in[2];
  const float* gamma = (const float*)d_in[3];
  const float* beta  = (const float*)d_in[4];
  const float* mean  = (const float*)d_in[5];
  const float* var   = (const float*)d_in[6];
  const float* pw    = (const float*)d_in[7];
  float* out = (float*)d_out;

  // ws: p 64Mi@0 | pp 16Mi@64Mi | eTh 1Mi@80Mi | eTl 1Mi@81Mi | flags 16Ki@84Mi
  unsigned short* p_bf = (unsigned short*)d_ws;
  float* pp  = (float*)((char*)d_ws + ((size_t)64 << 20));
  unsigned short* eTh = (unsigned short*)((char*)d_ws + ((size_t)80 << 20));
  unsigned short* eTl = (unsigned short*)((char*)d_ws + ((size_t)81 << 20));
  unsigned char* flags = (unsigned char*)((char*)d_ws + ((size_t)84 << 20));

  hipMemsetAsync(flags, 0, 2 * 32 * 256, stream);
  k_conv_part<<<dim3(32, 2, 16), 256, 0, stream>>>(x, cw, pp);
  k_bn<<<dim3(64, 2), 256, 0, stream>>>(pp, cb, gamma, beta, mean, var, pw,
                                        eTh, eTl);
  k_gsm<<<dim3(NPIX / 32, 2), 1024, 0, stream>>>(eTh, eTl, p_bf, flags);
  k_out_mfma<<<dim3(32, 4, 2), 256, 0, stream>>>(p_bf, x, out, flags);
}

// Round 12
// 269.366 us; speedup vs baseline: 1.3801x; 1.3801x over previous
//
#include <hip/hip_runtime.h>
#include <math.h>

#define NPIX 4096
#define CR   64
#define CIN  256
#define HW   64
#define CSPLIT 8    // conv c-split partials

typedef __attribute__((ext_vector_type(8))) short s16x8;
typedef __attribute__((ext_vector_type(4))) float f32x4;

__device__ __forceinline__ unsigned short f2bf(float f) {
  union { float f; unsigned u; } a; a.f = f;
  return (unsigned short)((a.u + 0x7FFF + ((a.u >> 16) & 1)) >> 16);
}
__device__ __forceinline__ float bf2f(unsigned short h) {
  union { unsigned u; float f; } a; a.u = (unsigned)h << 16; return a.f;
}

// ---------------------------------------------------------------------------
// K0: pack conv weights into MFMA A-fragment order, split bf16 hi/lo.
// wpk[(cs*9+tap)*4+dt][lane l][8]:  w[d=dt*16+(l&15)][c=cs*32+(l>>4)*8+j]
// ---------------------------------------------------------------------------
__global__ __launch_bounds__(256) void k_wsplit(
    const float* __restrict__ cw, unsigned short* __restrict__ wpkh,
    unsigned short* __restrict__ wpkl) {
  int idx = blockIdx.x * 256 + threadIdx.x;
  if (idx >= 8 * 9 * 4 * 64) return;
  int l = idx & 63;
  int dt = (idx >> 6) & 3;
  int r2 = idx >> 8;
  int tap = r2 % 9;
  int cs = r2 / 9;
  int lc = l & 15, lq = l >> 4;
  int d = dt * 16 + lc;
  s16x8 oh, ol;
#pragma unroll
  for (int j = 0; j < 8; ++j) {
    int c = cs * 32 + lq * 8 + j;
    float w = cw[(size_t)d * 2304 + c * 9 + tap];
    unsigned short hi = f2bf(w);
    oh[j] = (short)hi;
    ol[j] = (short)f2bf(w - bf2f(hi));
  }
  *(s16x8*)&wpkh[(size_t)idx * 8] = oh;
  *(s16x8*)&wpkl[(size_t)idx * 8] = ol;
}

// ---------------------------------------------------------------------------
// K1: conv partials via MFMA implicit GEMM. Block = 256 thr (4 waves),
// output 64d x 256n (4 image rows, wave = 1 row), c-chunk 32 (cs of 8).
// Per tap: A = packed split-W frags (global, L2), B = bf16 x-slab from LDS.
// Writes pp[(b*8+cs)*64+d][n] fp32 partials (k_bn reduces).
// ---------------------------------------------------------------------------
__global__ __launch_bounds__(256) void k_conv_mfma(
    const float* __restrict__ x, const unsigned short* __restrict__ wpkh,
    const unsigned short* __restrict__ wpkl, float* __restrict__ pp) {
  const int ng = blockIdx.x;        // rows h0..h0+3
  const int cs = blockIdx.y;        // c chunk of 32
  const int b  = blockIdx.z;
  const int h0 = ng * 4;
  const int c0 = cs * 32;
  const int tid = threadIdx.x;
  const int l = tid & 63, wid = tid >> 6;   // wave = image row h0+wid
  const int lc = l & 15, lq = l >> 4;

  __shared__ __align__(16) unsigned short xs[6][66][40]; // [r][w+1][c] bf16

  // stage: rows h0-1..h0+4, w -1..64, c0..c0+31 (w-contiguous per thread run)
  for (int i = tid; i < 6 * 66 * 32; i += 256) {
    int w = i % 66;
    int t2 = i / 66;            // 0..191
    int c = t2 & 31;
    int r = t2 >> 5;            // 0..5
    int hg = h0 - 1 + r, wg = w - 1;
    float v = 0.f;
    if (hg >= 0 && hg < HW && wg >= 0 && wg < HW)
      v = x[((size_t)(b * CIN + c0 + c) << 12) + hg * HW + wg];
    xs[r][w][c] = f2bf(v);
  }
  __syncthreads();

  f32x4 acc[4][4];   // [dt][nt]
#pragma unroll
  for (int dt = 0; dt < 4; ++dt)
#pragma unroll
    for (int nt = 0; nt < 4; ++nt)
#pragma unroll
      for (int q = 0; q < 4; ++q) acc[dt][nt][q] = 0.f;

#pragma unroll
  for (int tap = 0; tap < 9; ++tap) {
    const int kh = tap / 3, kw = tap - kh * 3;
    s16x8 Ah[4], Al[4];
#pragma unroll
    for (int dt = 0; dt < 4; ++dt) {
      size_t widx = ((size_t)((cs * 9 + tap) * 4 + dt) * 64 + l) * 8;
      Ah[dt] = *(const s16x8*)&wpkh[widx];
      Al[dt] = *(const s16x8*)&wpkl[widx];
    }
#pragma unroll
    for (int nt = 0; nt < 4; ++nt) {
      s16x8 bf = *(const s16x8*)&xs[wid + kh][nt * 16 + lc + kw][lq * 8];
#pragma unroll
      for (int dt = 0; dt < 4; ++dt) {
        acc[dt][nt] = __builtin_amdgcn_mfma_f32_16x16x32_bf16(Ah[dt], bf, acc[dt][nt], 0, 0, 0);
        acc[dt][nt] = __builtin_amdgcn_mfma_f32_16x16x32_bf16(Al[dt], bf, acc[dt][nt], 0, 0, 0);
      }
    }
  }

  float* pr = pp + ((size_t)((b * CSPLIT + cs) * 64) << 12);
#pragma unroll
  for (int dt = 0; dt < 4; ++dt)
#pragma unroll
    for (int nt = 0; nt < 4; ++nt)
#pragma unroll
      for (int q = 0; q < 4; ++q) {
        int d = dt * 16 + lq * 4 + q;
        int n = ng * 256 + wid * 64 + nt * 16 + lc;
        pr[((size_t)d << 12) + n] = acc[dt][nt][q];
      }
}

// ---------------------------------------------------------------------------
// K2: reduce partials + bias + BN + PReLU, split e into bf16 hi/lo, write
// eT [b][n_phys][64]; n -> phys: g=n>>8, i=n&255, np=(g<<8)|((i&15)<<4)|(i>>4)
// ---------------------------------------------------------------------------
__global__ __launch_bounds__(256) void k_bn(
    const float* __restrict__ pp, const float* __restrict__ cb,
    const float* __restrict__ gamma, const float* __restrict__ beta,
    const float* __restrict__ mean, const float* __restrict__ var,
    const float* __restrict__ pw, unsigned short* __restrict__ eTh,
    unsigned short* __restrict__ eTl) {
  const int n0 = blockIdx.x * 64;
  const int b  = blockIdx.y;
  const int tid = threadIdx.x;
  __shared__ float et[64][65];

  const float slope = pw[0];
#pragma unroll 4
  for (int dd = 0; dd < 16; ++dd) {
    int d = dd * 4 + (tid >> 6);
    int n = tid & 63;
    float s = 0.f;
#pragma unroll
    for (int cs = 0; cs < CSPLIT; ++cs)
      s += pp[((size_t)((b * CSPLIT + cs) * 64 + d) << 12) + n0 + n];
    float scale = gamma[d] / sqrtf(var[d] + 1e-5f);
    float y = (s + cb[d] - mean[d]) * scale + beta[d];
    y = (y >= 0.f) ? y : slope * y;
    et[d][n] = y;
  }
  __syncthreads();
#pragma unroll 4
  for (int w = 0; w < 16; ++w) {
    int n = w * 4 + (tid >> 6);
    int d = tid & 63;
    float v = et[d][n];
    unsigned short hi = f2bf(v);
    unsigned short lo = f2bf(v - bf2f(hi));
    int nl = n0 + n;
    int g = nl >> 8, i = nl & 255;
    int np = (g << 8) | ((i & 15) << 4) | (i >> 4);
    size_t off = (((size_t)b << 12) + np) * 64 + d;
    eTh[off] = hi;
    eTl[off] = lo;
  }
}

// ---------------------------------------------------------------------------
// K3: Gram via split-bf16 MFMA + in-register Michelot sparsemax.
// (round-10 proven version: 16-row stripe, 1024 thr, VGPR 64, no spill)
// ---------------------------------------------------------------------------
__global__ __launch_bounds__(1024) void k_gsm(
    const unsigned short* __restrict__ eTh, const unsigned short* __restrict__ eTl,
    unsigned short* __restrict__ p, unsigned char* __restrict__ flags) {
  const int n0 = blockIdx.x * 16;
  const int b  = blockIdx.y;
  const int tid = threadIdx.x;
  const int l = tid & 63, wid = tid >> 6;   // 16 waves
  const int lc = l & 15, lq = l >> 4;

  __shared__ __align__(16) unsigned short eah[16][72];
  __shared__ __align__(16) unsigned short eal[16][72];
  __shared__ float rs[16][16];
  __shared__ int   rc[16][16];
  __shared__ float stau[16];
  __shared__ int   sprev[16];
  __shared__ int   schg;

  const size_t ebase = ((size_t)b << 12) * 64;   // b*4096*64

  {  // stage A stripe: logical rows n0..n0+15 live at phys (g<<8)|(r<<4)|a
    int d = tid & 63, r = (tid >> 6) & 15;
    int g = n0 >> 8, a = (n0 & 255) >> 4;
    int np = (g << 8) | (r << 4) | a;
    size_t off = ebase + (size_t)np * 64 + d;
    eah[r][d] = eTh[off];
    eal[r][d] = eTl[off];
  }
  if (tid < 16) sprev[tid] = NPIX + 1;
  __syncthreads();

  f32x4 acc[16];
#pragma unroll
  for (int t = 0; t < 16; ++t)
#pragma unroll
    for (int q = 0; q < 4; ++q) acc[t][q] = 0.f;

  const int mbase = wid * 256;
#pragma unroll
  for (int kc = 0; kc < 2; ++kc) {
    s16x8 ah = *(const s16x8*)&eah[lc][kc * 32 + lq * 8];
    s16x8 al = *(const s16x8*)&eal[lc][kc * 32 + lq * 8];
#pragma unroll
    for (int t = 0; t < 16; ++t) {
      size_t off = ebase + (size_t)(mbase + t * 16 + lc) * 64 + kc * 32 + lq * 8;
      s16x8 bh = *(const s16x8*)&eTh[off];
      s16x8 bl = *(const s16x8*)&eTl[off];
      acc[t] = __builtin_amdgcn_mfma_f32_16x16x32_bf16(ah, bh, acc[t], 0, 0, 0);
      acc[t] = __builtin_amdgcn_mfma_f32_16x16x32_bf16(ah, bl, acc[t], 0, 0, 0);
      acc[t] = __builtin_amdgcn_mfma_f32_16x16x32_bf16(al, bh, acc[t], 0, 0, 0);
    }
  }

  // tau init = rowmax - 1
  {
    float mx[4];
#pragma unroll
    for (int q = 0; q < 4; ++q) {
      float m = acc[0][q];
#pragma unroll
      for (int t = 1; t < 16; ++t) m = fmaxf(m, acc[t][q]);
      mx[q] = m;
    }
#pragma unroll
    for (int o = 1; o <= 8; o <<= 1)
#pragma unroll
      for (int q = 0; q < 4; ++q) mx[q] = fmaxf(mx[q], __shfl_xor(mx[q], o));
    if (lc == 0)
#pragma unroll
      for (int q = 0; q < 4; ++q) rs[wid][lq * 4 + q] = mx[q];
  }
  __syncthreads();
  if (tid < 16) {
    float m = rs[0][tid];
#pragma unroll
    for (int w = 1; w < 16; ++w) m = fmaxf(m, rs[w][tid]);
    stau[tid] = m - 1.0f;
  }

  // Michelot iterations
  for (int it = 0; it < 64; ++it) {
    __syncthreads();
    float tl[4];
#pragma unroll
    for (int q = 0; q < 4; ++q) tl[q] = stau[lq * 4 + q];
    if (tid == 0) schg = 0;
    float s[4]; int c[4];
#pragma unroll
    for (int q = 0; q < 4; ++q) { s[q] = 0.f; c[q] = 0; }
#pragma unroll
    for (int t = 0; t < 16; ++t)
#pragma unroll
      for (int q = 0; q < 4; ++q) {
        float v = acc[t][q];
        if (v > tl[q]) { s[q] += v; ++c[q]; }
      }
#pragma unroll
    for (int o = 1; o <= 8; o <<= 1)
#pragma unroll
      for (int q = 0; q < 4; ++q) {
        s[q] += __shfl_xor(s[q], o);
        c[q] += __shfl_xor(c[q], o);
      }
    if (lc == 0)
#pragma unroll
      for (int q = 0; q < 4; ++q) { rs[wid][lq * 4 + q] = s[q]; rc[wid][lq * 4 + q] = c[q]; }
    __syncthreads();
    if (tid < 16) {
      float ss = 0.f; int cc = 0;
#pragma unroll
      for (int w = 0; w < 16; ++w) { ss += rs[w][tid]; cc += rc[w][tid]; }
      stau[tid] = (ss - 1.f) / (float)cc;
      if (cc != sprev[tid]) { sprev[tid] = cc; schg = 1; }
    }
    __syncthreads();
    if (schg == 0) break;
  }

  // p: lane patch = 4 rows x 16 contiguous cols; sparse b128 stores
  float tw[4];
#pragma unroll
  for (int q = 0; q < 4; ++q) tw[q] = stau[lq * 4 + q];
  s16x8 oA[4], oB[4];
  int anyL = 0;
#pragma unroll
  for (int q = 0; q < 4; ++q) {
#pragma unroll
    for (int t = 0; t < 8; ++t) {
      float pv = fmaxf(acc[t][q] - tw[q], 0.f);
      anyL |= (pv > 0.f);
      oA[q][t] = (short)f2bf(pv);
    }
#pragma unroll
    for (int t = 0; t < 8; ++t) {
      float pv = fmaxf(acc[t + 8][q] - tw[q], 0.f);
      anyL |= (pv > 0.f);
      oB[q][t] = (short)f2bf(pv);
    }
  }
  unsigned long long bal = __ballot(anyL != 0);
  const unsigned long long M0 = 0x00FF00FF00FF00FFULL;  // lanes lc<8
  bool w0 = (bal & M0) != 0;
  bool w1 = (bal & ~M0) != 0;
  bool mine = (lc < 8) ? w0 : w1;
  if (mine) {
#pragma unroll
    for (int q = 0; q < 4; ++q) {
      unsigned short* pr =
          p + ((size_t)(b * NPIX + n0 + lq * 4 + q) << 12) + mbase + lc * 16;
      *(s16x8*)pr = oA[q];
      *(s16x8*)(pr + 8) = oB[q];
    }
  }
  if (l == 0) {
    int stripe = blockIdx.x;                       // 0..255
    if (w0) flags[(b << 13) | ((wid * 2 + 0) << 8) | stripe] = 1;
    if (w1) flags[(b << 13) | ((wid * 2 + 1) << 8) | stripe] = 1;
  }
}

// ---------------------------------------------------------------------------
// K4: out = x @ p + x, bf16 MFMA, skipping zero k-tiles; zero-fill halves
// whose 16-row flag is unset (their p was never written).
// ---------------------------------------------------------------------------
__global__ __launch_bounds__(256) void k_out_mfma(
    const unsigned short* __restrict__ pb, const float* __restrict__ x,
    float* __restrict__ out, const unsigned char* __restrict__ flags) {
  const int m0 = blockIdx.x * 128;
  const int c0 = blockIdx.y * 64;
  const int b  = blockIdx.z;
  const int tid = threadIdx.x;
  const int l = tid & 63, wid = tid >> 6;
  const int wr = wid >> 1, wc = wid & 1;

  __shared__ unsigned short As[64][42];
  __shared__ unsigned short Bs[128][42];
  __shared__ unsigned char fl[256];

  fl[tid] = flags[(b << 13) | (blockIdx.x << 8) | tid];   // 256 stripes

  f32x4 acc[2][4];
#pragma unroll
  for (int i = 0; i < 2; ++i)
#pragma unroll
    for (int j = 0; j < 4; ++j)
#pragma unroll
      for (int q = 0; q < 4; ++q) acc[i][j][q] = 0.f;

  const int arow = tid >> 2;
  const int akc  = (tid & 3) * 8;
  const float* axsrc = x + ((size_t)(b * CIN + c0 + arow) << 12) + akc;
  const int bm = (tid & 31) * 4;
  const int bk = (tid >> 5) * 4;
  const unsigned short* bsrc = pb + ((size_t)(b * NPIX + bk) << 12) + m0 + bm;
  const int myhalf = bk >> 4;

  __syncthreads();                    // fl ready

  for (int k0 = 0; k0 < NPIX; k0 += 32) {
    const int s0 = k0 >> 4;
    const int have0 = fl[s0], have1 = fl[s0 + 1];
    if (!have0 && !have1) continue;   // block-uniform skip
    __syncthreads();
    float4 A0 = *(const float4*)(axsrc + k0);
    float4 A1 = *(const float4*)(axsrc + k0 + 4);
    s16x8 ap;
    ap[0] = (short)f2bf(A0.x); ap[1] = (short)f2bf(A0.y);
    ap[2] = (short)f2bf(A0.z); ap[3] = (short)f2bf(A0.w);
    ap[4] = (short)f2bf(A1.x); ap[5] = (short)f2bf(A1.y);
    ap[6] = (short)f2bf(A1.z); ap[7] = (short)f2bf(A1.w);
    *(s16x8*)&As[arow][akc] = ap;
    if ((myhalf ? have1 : have0)) {
      const unsigned short* bp = bsrc + ((size_t)k0 << 12);
      ushort4 L0 = *(const ushort4*)(bp);
      ushort4 L1 = *(const ushort4*)(bp + 4096);
      ushort4 L2 = *(const ushort4*)(bp + 8192);
      ushort4 L3 = *(const ushort4*)(bp + 12288);
      *(ushort4*)&Bs[bm + 0][bk] = make_ushort4(L0.x, L1.x, L2.x, L3.x);
      *(ushort4*)&Bs[bm + 1][bk] = make_ushort4(L0.y, L1.y, L2.y, L3.y);
      *(ushort4*)&Bs[bm + 2][bk] = make_ushort4(L0.z, L1.z, L2.z, L3.z);
      *(ushort4*)&Bs[bm + 3][bk] = make_ushort4(L0.w, L1.w, L2.w, L3.w);
    } else {
      ushort4 zz = make_ushort4(0, 0, 0, 0);
      *(ushort4*)&Bs[bm + 0][bk] = zz;
      *(ushort4*)&Bs[bm + 1][bk] = zz;
      *(ushort4*)&Bs[bm + 2][bk] = zz;
      *(ushort4*)&Bs[bm + 3][bk] = zz;
    }
    __syncthreads();

    s16x8 a[2], bb[4];
    const int kg = l >> 4;
#pragma unroll
    for (int i = 0; i < 2; ++i) {
      int row = wr * 32 + i * 16 + (l & 15);
      a[i] = *(const s16x8*)&As[row][kg * 8];
    }
#pragma unroll
    for (int j = 0; j < 4; ++j) {
      int n = wc * 64 + j * 16 + (l & 15);
      bb[j] = *(const s16x8*)&Bs[n][kg * 8];
    }
#pragma unroll
    for (int i = 0; i < 2; ++i)
#pragma unroll
      for (int j = 0; j < 4; ++j)
        acc[i][j] = __builtin_amdgcn_mfma_f32_16x16x32_bf16(
            a[i], bb[j], acc[i][j], 0, 0, 0);
  }

#pragma unroll
  for (int i = 0; i < 2; ++i)
#pragma unroll
    for (int j = 0; j < 4; ++j)
#pragma unroll
      for (int q = 0; q < 4; ++q) {
        int c = c0 + wr * 32 + i * 16 + (l >> 4) * 4 + q;
        int m = m0 + wc * 64 + j * 16 + (l & 15);
        size_t off = ((size_t)(b * CIN + c) << 12) + m;
        out[off] = acc[i][j][q] + x[off];
      }
}

// ---------------------------------------------------------------------------
extern "C" void kernel_launch(void* const* d_in, const int* in_sizes, int n_in,
                              void* d_out, int out_size, void* d_ws, size_t ws_size,
                              hipStream_t stream) {
  const float* x     = (const float*)d_in[0];
  const float* cw    = (const float*)d_in[1];
  const float* cb    = (const float*)d_in[2];
  const float* gamma = (const float*)d_in[3];
  const float* beta  = (const float*)d_in[4];
  const float* mean  = (const float*)d_in[5];
  const float* var   = (const float*)d_in[6];
  const float* pw    = (const float*)d_in[7];
  float* out = (float*)d_out;

  // ws: p 64Mi@0 | pp 16Mi@64Mi | eTh 1Mi@80Mi | eTl 1Mi@81Mi |
  //     flags 16Ki@84Mi | wpkh 288Ki@85Mi | wpkl 288Ki@86Mi
  unsigned short* p_bf = (unsigned short*)d_ws;
  float* pp  = (float*)((char*)d_ws + ((size_t)64 << 20));
  unsigned short* eTh = (unsigned short*)((char*)d_ws + ((size_t)80 << 20));
  unsigned short* eTl = (unsigned short*)((char*)d_ws + ((size_t)81 << 20));
  unsigned char* flags = (unsigned char*)((char*)d_ws + ((size_t)84 << 20));
  unsigned short* wpkh = (unsigned short*)((char*)d_ws + ((size_t)85 << 20));
  unsigned short* wpkl = (unsigned short*)((char*)d_ws + ((size_t)86 << 20));

  hipMemsetAsync(flags, 0, 2 * 32 * 256, stream);
  k_wsplit<<<72, 256, 0, stream>>>(cw, wpkh, wpkl);
  k_conv_mfma<<<dim3(16, 8, 2), 256, 0, stream>>>(x, wpkh, wpkl, pp);
  k_bn<<<dim3(64, 2), 256, 0, stream>>>(pp, cb, gamma, beta, mean, var, pw,
                                        eTh, eTl);
  k_gsm<<<dim3(NPIX / 16, 2), 1024, 0, stream>>>(eTh, eTl, p_bf, flags);
  k_out_mfma<<<dim3(32, 4, 2), 256, 0, stream>>>(p_bf, x, out, flags);
}